// Round 4
// baseline (1144.236 us; speedup 1.0000x reference)
//
#include <hip/hip_runtime.h>

// Problem constants (from reference)
constexpr int NN    = 16;              // neighbors per center
constexpr int NF    = 32;              // embedding features
constexpr int ROWW  = 3 + 3 * NF;      // 99 floats per (j,k) row
constexpr int PAIRS = NN * (NN - 1);   // 240 off-diagonal pairs
constexpr int PER_C = PAIRS * ROWW;    // 23760 floats per center
constexpr int GROUPS = PAIRS / 4;      // 60 groups of 4 rows
constexpr int GV4    = ROWW;           // 99 float4 slots per 4-row group (396 floats)

typedef float v4f __attribute__((ext_vector_type(4)));

// LDS float layout
constexpr int OFF_D   = 0;             // d[16]
constexpr int OFF_DJK = 16;            // d_jk_norm[16*16], idx j*16+k
constexpr int OFF_EI  = 16 + 256;      // emb_i[32]
constexpr int OFF_EJ  = 16 + 256 + 32; // emb_j_scaled[16*32], idx j*32+f (pre-divided by d[j])
constexpr int SMEM_F  = OFF_EJ + NN * NF; // 816 floats

// MEASUREMENT-PROBE ROUND: mirror all output stores into d_ws (distinct
// addresses, never validated) so kernel writes 2x bytes. Delta(total dur)
// = true kernel duration T, resolving the fill-vs-kernel decomposition
// ambiguity. Revert next round.

__global__ __launch_bounds__(256)
void angle_desc_kernel(const float* __restrict__ atoms_xyz,
                       const float* __restrict__ embed_table,
                       const float* __restrict__ dist_ij,
                       const int*   __restrict__ atom_types,
                       const int*   __restrict__ atom_i_idx,
                       const int*   __restrict__ atom_j_idx,
                       float* __restrict__ out_desc,
                       float* __restrict__ out_centers,
                       float* __restrict__ ws_mirror)   // nullptr if ws too small
{
    __shared__ float smem[SMEM_F];
    __shared__ int   s_jk[PAIRS];      // packed j | (k<<8) per off-diag row
    __shared__ float s_xyz[NN][3];
    __shared__ int   s_idx[NN];

    const int c   = blockIdx.x;
    const int tid = threadIdx.x;

    // ---- Phase 1: gather per-center scalars + build jk row table ----
    if (tid < NN) {
        float d = dist_ij[c * NN + tid];
        smem[OFF_D + tid] = d;
        int aj = atom_j_idx[c * NN + tid];
        s_idx[tid] = aj;
        s_xyz[tid][0] = atoms_xyz[aj * 3 + 0];
        s_xyz[tid][1] = atoms_xyz[aj * 3 + 1];
        s_xyz[tid][2] = atoms_xyz[aj * 3 + 2];
    } else if (tid >= 32 && tid < 32 + NF) {
        int f  = tid - 32;
        int ti = atom_types[atom_i_idx[c]];
        smem[OFF_EI + f] = embed_table[ti * NF + f];
    }
    if (tid < PAIRS) {                 // row -> (j,k) map, row-major off-diagonal
        int j  = tid / 15;
        int rr = tid - 15 * j;
        int k  = rr + (rr >= j ? 1 : 0);
        s_jk[tid] = j | (k << 8);
    }
    if (tid == 0) out_centers[c] = (float)atom_i_idx[c];   // output 1 (as float)
    __syncthreads();

    // ---- Phase 2: derived LDS tables ----
    for (int t2 = tid; t2 < NN * NF; t2 += 256) {
        int j = t2 >> 5, f = t2 & 31;
        int tj = atom_types[s_idx[j]];
        smem[OFF_EJ + t2] = embed_table[tj * NF + f] / smem[OFF_D + j];
    }
    if (tid < NN * NN) {
        int j = tid >> 4, k = tid & 15;
        float dx = s_xyz[j][0] - s_xyz[k][0];
        float dy = s_xyz[j][1] - s_xyz[k][1];
        float dz = s_xyz[j][2] - s_xyz[k][2];
        float djk = sqrtf(dx * dx + dy * dy + dz * dz);
        float dj = smem[OFF_D + j], dk = smem[OFF_D + k];
        float mx = fmaxf(dj, dk), mn = fminf(dj, dk);
        smem[OFF_DJK + tid] = (djk - mx + mn) / (2.0f * mn);
    }
    __syncthreads();

    // ---- Phase 3: team-of-128, one 4-row group (99 float4) per step ----
    const int team = tid >> 7;         // 0 or 1
    const int t    = tid & 127;        // slot within group
    if (t >= GV4) return;              // no further barriers below

    const int rA = (4 * t) / 99;       // first row-offset touched by this thread
    const int rB = (4 * t + 3) / 99;   // last (rA or rA+1)

    int  baseA[4], mJ[4], mK[4];
    bool selB[4];
    #pragma unroll
    for (int e = 0; e < 4; ++e) {
        int fl  = 4 * t + e;           // flat float index within the 396-float group
        int ro  = fl / 99;
        int col = fl - 99 * ro;
        selB[e] = (ro > rA);
        int b, mj, mk;
        if      (col == 0) { b = OFF_D;               mj = 1;  mk = 0;  }
        else if (col == 1) { b = OFF_D;               mj = 0;  mk = 1;  }
        else if (col == 2) { b = OFF_DJK;             mj = 16; mk = 1;  }
        else if (col < 35) { b = OFF_EI + (col - 3);  mj = 0;  mk = 0;  }
        else if (col < 67) { b = OFF_EJ + (col - 35); mj = 32; mk = 0;  }
        else               { b = OFF_EJ + (col - 67); mj = 0;  mk = 32; }
        baseA[e] = b; mJ[e] = mj; mK[e] = mk;
    }

    v4f* outv = reinterpret_cast<v4f*>(out_desc + (size_t)c * PER_C);
    v4f* wsv  = ws_mirror ? reinterpret_cast<v4f*>(ws_mirror + (size_t)c * PER_C) : nullptr;
    for (int g = team; g < GROUPS; g += 2) {
        int r0 = 4 * g;
        int pA = s_jk[r0 + rA];
        int pB = s_jk[r0 + rB];
        int jA = pA & 255, kA = pA >> 8;
        int jB = pB & 255, kB = pB >> 8;
        v4f o;
        #pragma unroll
        for (int e = 0; e < 4; ++e) {
            int j = selB[e] ? jB : jA;
            int k = selB[e] ? kB : kA;
            ((float*)&o)[e] = smem[baseA[e] + j * mJ[e] + k * mK[e]];
        }
        outv[g * GV4 + t] = o;
        if (wsv) wsv[g * GV4 + t] = o;     // probe: double the HBM write traffic
    }
}

extern "C" void kernel_launch(void* const* d_in, const int* in_sizes, int n_in,
                              void* d_out, int out_size, void* d_ws, size_t ws_size,
                              hipStream_t stream)
{
    const float* atoms_xyz  = (const float*)d_in[0];
    const float* embed      = (const float*)d_in[1];
    const float* dist       = (const float*)d_in[2];
    const int*   atom_types = (const int*)d_in[3];
    const int*   atom_i     = (const int*)d_in[4];
    const int*   atom_j     = (const int*)d_in[5];

    const int C = in_sizes[4];                 // N_CENTER = 10000
    float* out         = (float*)d_out;
    float* out_centers = out + (size_t)C * PER_C;

    // Probe mirror target: only if the workspace can hold a full output copy.
    // ws_size is constant across calls -> identical work every launch (graph-safe).
    float* ws_mirror = (ws_size >= (size_t)C * PER_C * sizeof(float))
                     ? (float*)d_ws : nullptr;

    hipLaunchKernelGGL(angle_desc_kernel, dim3(C), dim3(256), 0, stream,
                       atoms_xyz, embed, dist, atom_types, atom_i, atom_j,
                       out, out_centers, ws_mirror);
}

// Round 5
// 944.954 us; speedup vs baseline: 1.2109x; 1.2109x over previous
//
#include <hip/hip_runtime.h>

// Problem constants (from reference)
constexpr int NN    = 16;              // neighbors per center
constexpr int NF    = 32;              // embedding features
constexpr int ROWW  = 3 + 3 * NF;      // 99 floats per (j,k) row
constexpr int PAIRS = NN * (NN - 1);   // 240 off-diagonal pairs
constexpr int PER_C = PAIRS * ROWW;    // 23760 floats per center
constexpr int GROUPS = PAIRS / 4;      // 60 groups of 4 rows
constexpr int GV4    = ROWW;           // 99 float4 slots per 4-row group (396 floats)

typedef float v4f __attribute__((ext_vector_type(4)));

// LDS float layout
constexpr int OFF_D   = 0;             // d[16]
constexpr int OFF_DJK = 16;            // d_jk_norm[16*16], idx j*16+k
constexpr int OFF_EI  = 16 + 256;      // emb_i[32]
constexpr int OFF_EJ  = 16 + 256 + 32; // emb_j_scaled[16*32], idx j*32+f (pre-divided by d[j])
constexpr int SMEM_F  = OFF_EJ + NN * NF; // 816 floats

// Round-4 probe (d_ws store mirror) measured the kernel's true cost:
// Δtotal = 197 µs per extra 950 MB ⇒ kernel T ≈ 175 µs vs 151 µs write floor.
// This version is the reverted, final configuration (identical to round 3).

__global__ __launch_bounds__(256)
void angle_desc_kernel(const float* __restrict__ atoms_xyz,
                       const float* __restrict__ embed_table,
                       const float* __restrict__ dist_ij,
                       const int*   __restrict__ atom_types,
                       const int*   __restrict__ atom_i_idx,
                       const int*   __restrict__ atom_j_idx,
                       float* __restrict__ out_desc,
                       float* __restrict__ out_centers)
{
    __shared__ float smem[SMEM_F];
    __shared__ int   s_jk[PAIRS];      // packed j | (k<<8) per off-diag row
    __shared__ float s_xyz[NN][3];
    __shared__ int   s_idx[NN];

    const int c   = blockIdx.x;
    const int tid = threadIdx.x;

    // ---- Phase 1: gather per-center scalars + build jk row table ----
    if (tid < NN) {
        float d = dist_ij[c * NN + tid];
        smem[OFF_D + tid] = d;
        int aj = atom_j_idx[c * NN + tid];
        s_idx[tid] = aj;
        s_xyz[tid][0] = atoms_xyz[aj * 3 + 0];
        s_xyz[tid][1] = atoms_xyz[aj * 3 + 1];
        s_xyz[tid][2] = atoms_xyz[aj * 3 + 2];
    } else if (tid >= 32 && tid < 32 + NF) {
        int f  = tid - 32;
        int ti = atom_types[atom_i_idx[c]];
        smem[OFF_EI + f] = embed_table[ti * NF + f];
    }
    if (tid < PAIRS) {                 // row -> (j,k) map, row-major off-diagonal
        int j  = tid / 15;
        int rr = tid - 15 * j;
        int k  = rr + (rr >= j ? 1 : 0);
        s_jk[tid] = j | (k << 8);
    }
    if (tid == 0) out_centers[c] = (float)atom_i_idx[c];   // output 1 (as float)
    __syncthreads();

    // ---- Phase 2: derived LDS tables ----
    for (int t2 = tid; t2 < NN * NF; t2 += 256) {
        int j = t2 >> 5, f = t2 & 31;
        int tj = atom_types[s_idx[j]];
        smem[OFF_EJ + t2] = embed_table[tj * NF + f] / smem[OFF_D + j];
    }
    if (tid < NN * NN) {
        int j = tid >> 4, k = tid & 15;
        float dx = s_xyz[j][0] - s_xyz[k][0];
        float dy = s_xyz[j][1] - s_xyz[k][1];
        float dz = s_xyz[j][2] - s_xyz[k][2];
        float djk = sqrtf(dx * dx + dy * dy + dz * dz);
        float dj = smem[OFF_D + j], dk = smem[OFF_D + k];
        float mx = fmaxf(dj, dk), mn = fminf(dj, dk);
        smem[OFF_DJK + tid] = (djk - mx + mn) / (2.0f * mn);
    }
    __syncthreads();

    // ---- Phase 3: team-of-128, one 4-row group (99 float4) per step.
    //      Per-thread slot phase is loop-invariant: column-case decode hoisted;
    //      in-loop addr = base + j*mJ + k*mK (2 mads) + 1 ds_read per element.
    const int team = tid >> 7;         // 0 or 1
    const int t    = tid & 127;        // slot within group
    if (t >= GV4) return;              // no further barriers below

    const int rA = (4 * t) / 99;       // first row-offset touched by this thread
    const int rB = (4 * t + 3) / 99;   // last (rA or rA+1)

    int  baseA[4], mJ[4], mK[4];
    bool selB[4];
    #pragma unroll
    for (int e = 0; e < 4; ++e) {
        int fl  = 4 * t + e;           // flat float index within the 396-float group
        int ro  = fl / 99;
        int col = fl - 99 * ro;
        selB[e] = (ro > rA);
        int b, mj, mk;
        if      (col == 0) { b = OFF_D;               mj = 1;  mk = 0;  }
        else if (col == 1) { b = OFF_D;               mj = 0;  mk = 1;  }
        else if (col == 2) { b = OFF_DJK;             mj = 16; mk = 1;  }
        else if (col < 35) { b = OFF_EI + (col - 3);  mj = 0;  mk = 0;  }
        else if (col < 67) { b = OFF_EJ + (col - 35); mj = 32; mk = 0;  }
        else               { b = OFF_EJ + (col - 67); mj = 0;  mk = 32; }
        baseA[e] = b; mJ[e] = mj; mK[e] = mk;
    }

    v4f* outv = reinterpret_cast<v4f*>(out_desc + (size_t)c * PER_C);
    for (int g = team; g < GROUPS; g += 2) {
        int r0 = 4 * g;
        int pA = s_jk[r0 + rA];
        int pB = s_jk[r0 + rB];
        int jA = pA & 255, kA = pA >> 8;
        int jB = pB & 255, kB = pB >> 8;
        v4f o;
        #pragma unroll
        for (int e = 0; e < 4; ++e) {
            int j = selB[e] ? jB : jA;
            int k = selB[e] ? kB : kA;
            ((float*)&o)[e] = smem[baseA[e] + j * mJ[e] + k * mK[e]];
        }
        outv[g * GV4 + t] = o;
    }
}

extern "C" void kernel_launch(void* const* d_in, const int* in_sizes, int n_in,
                              void* d_out, int out_size, void* d_ws, size_t ws_size,
                              hipStream_t stream)
{
    const float* atoms_xyz  = (const float*)d_in[0];
    const float* embed      = (const float*)d_in[1];
    const float* dist       = (const float*)d_in[2];
    const int*   atom_types = (const int*)d_in[3];
    const int*   atom_i     = (const int*)d_in[4];
    const int*   atom_j     = (const int*)d_in[5];

    const int C = in_sizes[4];                 // N_CENTER = 10000
    float* out         = (float*)d_out;
    float* out_centers = out + (size_t)C * PER_C;

    hipLaunchKernelGGL(angle_desc_kernel, dim3(C), dim3(256), 0, stream,
                       atoms_xyz, embed, dist, atom_types, atom_i, atom_j,
                       out, out_centers);
}